// Round 5
// baseline (551.379 us; speedup 1.0000x reference)
//
#include <hip/hip_runtime.h>
#include <math.h>

// ---------------- problem constants (fixed by setup_inputs) ----------------
constexpr int D   = 64;
constexpr int H   = 8;
constexpr int HD  = 8;
constexpr int NL  = 3;
constexpr int FFNx= 256;
constexpr int Bb  = 4;
constexpr int Ss  = 2048;
constexpr int NT  = Bb * Ss;        // 8192 tokens
constexpr int MAXC= 1024;
constexpr int MCL = 16;

// attention task decomposition: uniform tasks, chunk-major enumeration
constexpr int QW   = 128;            // queries per wave (2 per lane)
constexpr int CH   = 128;            // keys per chunk task (== QW -> uniform)
constexpr int TPB  = 136;            // tasks per (b,h): sum_{s=0..15} (16-s)
constexpr int NTASK= 32 * TPB;       // 4352 waves
constexpr int PBSZ = 1152;           // floats per partial: l(128) + o(1024)

// ---------------- workspace layout (float elements) ----------------
constexpr size_t WX  = 0;                        // [NT*D] = 524288
constexpr size_t WQ  = 524288;                   // [NT*D] (U alias, needs NT*FFN)
constexpr size_t WKV = 2621440;                  // [32*2048*16] interleaved K|V
constexpr size_t WO  = 3670016;                  // [NT*D]
constexpr size_t WPB = 4194304;                  // [NTASK*PBSZ] attn partials
constexpr size_t WU  = WQ;                       // [NT*FFN] aliases Q
constexpr size_t WL1 = 9764864;                  // [NT]
constexpr size_t WEM = WL1 + NT;                 // [NT] int
constexpr size_t WCP = WEM + NT;                 // [NT] int
constexpr size_t WCT = WCP + NT;                 // [Ss*4]
constexpr size_t WST = WCT + Ss*4;               // [Ss*4]  (end ~9.81M floats)

constexpr float LOG2E = 1.4426950408889634f;

__device__ __forceinline__ float rdlane(float v, int l) {
    return __builtin_bit_cast(float, __builtin_amdgcn_readlane(__builtin_bit_cast(int, v), l));
}

// ---------------- init: copy x -> X, build rope tables ----------------
__global__ void k_init(const float* __restrict__ x, float* __restrict__ X,
                       float* __restrict__ ct, float* __restrict__ st) {
    int i = blockIdx.x * blockDim.x + threadIdx.x;
    constexpr int N4 = NT * D / 4;
    if (i < N4) ((float4*)X)[i] = ((const float4*)x)[i];
    if (i < Ss * 4) {
        int s = i >> 2, f = i & 3;
        const float fr[4] = {1.0f, 0.1f, 0.01f, 0.001f};
        float ang = (float)s * fr[f];
        ct[i] = cosf(ang);
        st[i] = sinf(ang);
    }
}

// ---------------- rmsnorm + QKV + rope (wave-per-token, readlane bcast) ----
// Q -> [b,s,h*8+e]; K,V -> interleaved KV[bh][s][0..7=K, 8..15=V]
__global__ __launch_bounds__(256) void k_qkv(
    const float* __restrict__ X, const float* __restrict__ Wq,
    const float* __restrict__ Wk, const float* __restrict__ Wv,
    const float* __restrict__ g1, const float* __restrict__ ct,
    const float* __restrict__ st, float* __restrict__ Q,
    float* __restrict__ KV) {
    __shared__ float wq_s[D*D], wk_s[D*D], wv_s[D*D];
    __shared__ float g_s[D];
    int tid = threadIdx.x;
    for (int i = tid; i < D*D; i += 256) {
        wq_s[i] = Wq[i]; wk_s[i] = Wk[i]; wv_s[i] = Wv[i];
    }
    if (tid < D) g_s[tid] = g1[tid];
    __syncthreads();
    int w = tid >> 6, d = tid & 63;
    int t0 = blockIdx.x * 32;
    for (int it = 0; it < 8; ++it) {
        int t = t0 + it*4 + w;
        float xv = X[t*D + d];
        float ss = xv * xv;
        #pragma unroll
        for (int off = 32; off; off >>= 1) ss += __shfl_xor(ss, off);
        float r = 1.0f / sqrtf(ss * (1.0f/D) + 1e-6f);
        float h = xv * g_s[d] * r;
        float aq = 0.f, ak = 0.f, av = 0.f;
        #pragma unroll
        for (int j = 0; j < D; ++j) {
            float hj = rdlane(h, j);
            aq += hj * wq_s[j*D + d];
            ak += hj * wk_s[j*D + d];
            av += hj * wv_s[j*D + d];
        }
        int s  = t & (Ss - 1);
        int e  = d & 7;
        int fi = e & 3;
        float c  = ct[s*4 + fi];
        float sn = st[s*4 + fi];
        float pq = __shfl_xor(aq, 4);
        float pk = __shfl_xor(ak, 4);
        float rq, rk;
        if (e < 4) { rq = aq*c - pq*sn; rk = ak*c - pk*sn; }
        else       { rq = pq*sn + aq*c; rk = pk*sn + ak*c; }
        Q[t*D + d] = rq;
        int bq = t >> 11;
        int hh = d >> 3;
        float* kvp = KV + ((((size_t)(bq*H + hh))*Ss + s) << 4);
        kvp[e]     = rk;
        kvp[8 + e] = av;
    }
}

// ---------------- fused attention inner loop (fixed exp bias, prefetch) ---
template<bool DIAG>
__device__ __forceinline__ void attn_loop(
    const float4* __restrict__ kvb, int L,
    float4 qa0, float4 qb0, float4 qa1, float4 qb1,
    float& l0r, float& l1r, float* o0, float* o1) {
    float l0 = 0.f, l1 = 0.f;
    float4 buf[4][4];
    #pragma unroll
    for (int i = 0; i < 4; ++i) {
        #pragma unroll
        for (int k = 0; k < 4; ++k) buf[i][k] = kvb[i*4 + k];
    }
    for (int j0 = 0; j0 < CH; j0 += 4) {
        #pragma unroll
        for (int i = 0; i < 4; ++i) {
            int j = j0 + i;
            float4 ka = buf[i][0], kb = buf[i][1];
            float4 va = buf[i][2], vb = buf[i][3];
            // prefetch key j+4 (tail reads spill into next region: safe)
            #pragma unroll
            for (int k = 0; k < 4; ++k) buf[i][k] = kvb[(size_t)(j + 4)*4 + k];
            float s0 = ka.x*qa0.x + ka.y*qa0.y + ka.z*qa0.z + ka.w*qa0.w
                     + kb.x*qb0.x + kb.y*qb0.y + kb.z*qb0.z + kb.w*qb0.w;
            float s1 = ka.x*qa1.x + ka.y*qa1.y + ka.z*qa1.z + ka.w*qa1.w
                     + kb.x*qb1.x + kb.y*qb1.y + kb.z*qb1.z + kb.w*qb1.w;
            if (DIAG) {
                if (j > L)      s0 = -1e30f;
                if (j > L + 64) s1 = -1e30f;
            }
            float p0 = exp2f(s0), p1 = exp2f(s1);
            l0 += p0; l1 += p1;
            o0[0] += p0*va.x; o0[1] += p0*va.y; o0[2] += p0*va.z; o0[3] += p0*va.w;
            o0[4] += p0*vb.x; o0[5] += p0*vb.y; o0[6] += p0*vb.z; o0[7] += p0*vb.w;
            o1[0] += p1*va.x; o1[1] += p1*va.y; o1[2] += p1*va.z; o1[3] += p1*va.w;
            o1[4] += p1*vb.x; o1[5] += p1*vb.y; o1[6] += p1*vb.z; o1[7] += p1*vb.w;
        }
    }
    l0r = l0; l1r = l1;
}

// ---------------- causal attention, uniform split-K, fixed-bias exp2 ------
// enumeration: s outer (off(s)=16s - s(s-1)/2), t = s..15 inner.
__global__ __launch_bounds__(256, 4) void k_attn2(
    const float* __restrict__ Qg, const float* __restrict__ KV,
    float* __restrict__ PB) {
    int wid = (blockIdx.x << 2) + (threadIdx.x >> 6);
    int L = threadIdx.x & 63;
    int bh = wid / TPB;
    int rem = wid - bh * TPB;
    int s = 0;
    while (rem >= 16 - s) { rem -= 16 - s; ++s; }
    int t = s + rem;
    int b = bh >> 3, h = bh & 7;
    int qmin = t * QW;
    int k0 = s * CH;

    const float SC = 0.35355339059327373f * LOG2E;   // 1/sqrt(8) * log2(e)
    const float* qp = Qg + ((size_t)(b*Ss + qmin + L))*D + h*HD;
    float4 qa0 = *(const float4*)(qp);
    float4 qb0 = *(const float4*)(qp + 4);
    float4 qa1 = *(const float4*)(qp + 64*D);
    float4 qb1 = *(const float4*)(qp + 64*D + 4);
    qa0.x*=SC; qa0.y*=SC; qa0.z*=SC; qa0.w*=SC;
    qb0.x*=SC; qb0.y*=SC; qb0.z*=SC; qb0.w*=SC;
    qa1.x*=SC; qa1.y*=SC; qa1.z*=SC; qa1.w*=SC;
    qb1.x*=SC; qb1.y*=SC; qb1.z*=SC; qb1.w*=SC;

    float l0, l1;
    float o0[8] = {0,0,0,0,0,0,0,0};
    float o1[8] = {0,0,0,0,0,0,0,0};

    const float4* kvb = (const float4*)(KV + (((size_t)bh*Ss + k0) << 4));
    if (s == t) attn_loop<true >(kvb, L, qa0, qb0, qa1, qb1, l0, l1, o0, o1);
    else        attn_loop<false>(kvb, L, qa0, qb0, qa1, qb1, l0, l1, o0, o1);

    float* pb = PB + (size_t)wid * PBSZ;
    pb[L]      = l0;
    pb[64 + L] = l1;
    #pragma unroll
    for (int e = 0; e < 8; ++e) {
        pb[128 + e*128 + L]      = o0[e];
        pb[128 + e*128 + 64 + L] = o1[e];
    }
}

// ---------------- combine partials -> O (plain sums, fixed bias) ----------
__global__ __launch_bounds__(128) void k_comb(const float* __restrict__ PB,
                                              float* __restrict__ Og) {
    int qs = threadIdx.x;           // 0..127
    int t  = blockIdx.x & 15;
    int bh = blockIdx.x >> 4;
    int b = bh >> 3, h = bh & 7;
    float Lx = 0.f;
    float O[8] = {0,0,0,0,0,0,0,0};
    for (int s3 = 0; s3 <= t; ++s3) {
        int idx = 16*s3 - (s3*(s3-1))/2 + (t - s3);
        const float* pb = PB + (size_t)(bh*TPB + idx) * PBSZ;
        Lx += pb[qs];
        #pragma unroll
        for (int e = 0; e < 8; ++e) O[e] += pb[128 + e*128 + qs];
    }
    float inv = 1.0f / Lx;
    float* op = Og + ((size_t)(b*Ss + t*QW + qs))*D + h*HD;
    #pragma unroll
    for (int e = 0; e < 8; ++e) op[e] = O[e] * inv;
}

// ---------------- x += O @ Wo (readlane bcast) ----------------
__global__ __launch_bounds__(256) void k_post1(
    float* __restrict__ X, const float* __restrict__ Og,
    const float* __restrict__ Wo) {
    __shared__ float ws_[D*D];
    int tid = threadIdx.x;
    for (int i = tid; i < D*D; i += 256) ws_[i] = Wo[i];
    __syncthreads();
    int w = tid >> 6, d = tid & 63;
    int t0 = blockIdx.x * 32;
    for (int it = 0; it < 8; ++it) {
        int t = t0 + it*4 + w;
        float ov = Og[t*D + d];
        float a = 0.f;
        #pragma unroll
        for (int j = 0; j < D; ++j) a += rdlane(ov, j) * ws_[j*D + d];
        X[t*D + d] += a;
    }
}

// ---------------- rms2 + W1 + gelu -> U (transposed LDS tile) -------------
__global__ __launch_bounds__(256) void k_ffn1(
    const float* __restrict__ X, const float* __restrict__ g2,
    const float* __restrict__ W1, float* __restrict__ U) {
    __shared__ __align__(16) float h2t[64][20];   // [dim][token], 80B rows
    __shared__ float part[16][16];
    __shared__ float g_s[D];
    int tid = threadIdx.x;
    if (tid < D) g_s[tid] = g2[tid];
    int t0 = blockIdx.x * 16;
    int tk = tid >> 4, li = tid & 15;
    float x0 = X[(t0+tk)*D + li];
    float x1 = X[(t0+tk)*D + li + 16];
    float x2 = X[(t0+tk)*D + li + 32];
    float x3 = X[(t0+tk)*D + li + 48];
    part[tk][li] = x0*x0 + x1*x1 + x2*x2 + x3*x3;
    __syncthreads();
    if (tid < 16) {
        float s = 0.f;
        #pragma unroll
        for (int i = 0; i < 16; ++i) s += part[tid][i];
        part[tid][0] = 1.0f / sqrtf(s * (1.0f/D) + 1e-6f);
    }
    __syncthreads();
    float r = part[tk][0];
    h2t[li][tk]      = x0 * g_s[li]      * r;
    h2t[li + 16][tk] = x1 * g_s[li + 16] * r;
    h2t[li + 32][tk] = x2 * g_s[li + 32] * r;
    h2t[li + 48][tk] = x3 * g_s[li + 48] * r;
    __syncthreads();
    int f = tid;
    float acc[16];
    #pragma unroll
    for (int i = 0; i < 16; ++i) acc[i] = 0.f;
    for (int j = 0; j < D; ++j) {
        float wv = W1[j*FFNx + f];
        const float4* hp = (const float4*)&h2t[j][0];
        float4 a0 = hp[0], a1 = hp[1], a2 = hp[2], a3 = hp[3];
        acc[0] += a0.x*wv;  acc[1] += a0.y*wv;  acc[2] += a0.z*wv;  acc[3] += a0.w*wv;
        acc[4] += a1.x*wv;  acc[5] += a1.y*wv;  acc[6] += a1.z*wv;  acc[7] += a1.w*wv;
        acc[8] += a2.x*wv;  acc[9] += a2.y*wv;  acc[10]+= a2.z*wv;  acc[11]+= a2.w*wv;
        acc[12]+= a3.x*wv;  acc[13]+= a3.y*wv;  acc[14]+= a3.z*wv;  acc[15]+= a3.w*wv;
    }
    #pragma unroll
    for (int i = 0; i < 16; ++i) {
        float u = acc[i];
        u = 0.5f * u * (1.0f + erff(u * 0.70710678118654752f));
        U[(t0 + i)*FFNx + f] = u;
    }
}

// ---------------- x += U @ W2 (transposed LDS tile) ----------------
__global__ __launch_bounds__(256) void k_ffn2(
    float* __restrict__ X, const float* __restrict__ U,
    const float* __restrict__ W2) {
    __shared__ __align__(16) float ult[FFNx][20];  // [f][token]
    __shared__ float red[4][16][D];
    int tid = threadIdx.x;
    int t0 = blockIdx.x * 16;
    #pragma unroll
    for (int k = 0; k < 16; ++k) ult[tid][k] = U[(t0 + k)*FFNx + tid];
    __syncthreads();
    int d = tid & 63, fp = tid >> 6;
    float acc[16];
    #pragma unroll
    for (int i = 0; i < 16; ++i) acc[i] = 0.f;
    for (int fo = 0; fo < 64; ++fo) {
        int f = fp*64 + fo;
        float wv = W2[f*D + d];
        const float4* up = (const float4*)&ult[f][0];
        float4 u0 = up[0], u1 = up[1], u2 = up[2], u3 = up[3];
        acc[0] += u0.x*wv;  acc[1] += u0.y*wv;  acc[2] += u0.z*wv;  acc[3] += u0.w*wv;
        acc[4] += u1.x*wv;  acc[5] += u1.y*wv;  acc[6] += u1.z*wv;  acc[7] += u1.w*wv;
        acc[8] += u2.x*wv;  acc[9] += u2.y*wv;  acc[10]+= u2.z*wv;  acc[11]+= u2.w*wv;
        acc[12]+= u3.x*wv;  acc[13]+= u3.y*wv;  acc[14]+= u3.z*wv;  acc[15]+= u3.w*wv;
    }
    #pragma unroll
    for (int i = 0; i < 16; ++i) red[fp][i][d] = acc[i];
    __syncthreads();
    int tk = tid >> 6;
    #pragma unroll
    for (int k = 0; k < 4; ++k) {
        int tt = tk + k*4;
        float sum = red[0][tt][d] + red[1][tt][d] + red[2][tt][d] + red[3][tt][d];
        X[(t0 + tt)*D + d] += sum;
    }
}

// ---------------- head ----------------
__global__ __launch_bounds__(256) void k_head(
    const float* __restrict__ X, const float* __restrict__ Wh,
    const float* __restrict__ bh, float* __restrict__ logit1,
    int* __restrict__ em) {
    int tid = threadIdx.x;
    int w = tid >> 6, d = tid & 63;
    int t = blockIdx.x*4 + w;
    float xv = X[t*D + d];
    float p0 = xv * Wh[d*2];
    float p1 = xv * Wh[d*2 + 1];
    #pragma unroll
    for (int off = 32; off; off >>= 1) {
        p0 += __shfl_xor(p0, off);
        p1 += __shfl_xor(p1, off);
    }
    if (d == 0) {
        float l0 = p0 + bh[0], l1 = p1 + bh[1];
        em[t] = (l0 > l1) ? 1 : 0;
        logit1[t] = l1;
    }
}

// ---------------- reg term ----------------
__global__ void k_reg(const float* __restrict__ logit1, float* __restrict__ outreg) {
    __shared__ float red[256];
    int tid = threadIdx.x;
    float s = 0.f;
    for (int i = tid; i < NT; i += 256) s += logit1[i];
    red[tid] = s;
    __syncthreads();
    for (int off = 128; off; off >>= 1) {
        if (tid < off) red[tid] += red[tid + off];
        __syncthreads();
    }
    if (tid == 0) *outreg = red[0] * (1.0f / NT);
}

// ---------------- per-batch scan ----------------
__global__ __launch_bounds__(256) void k_scan(const int* __restrict__ em,
                                              int* __restrict__ cp) {
    __shared__ int ssum[256], smax[256];
    __shared__ int sany, stot;
    int b = blockIdx.x, tid = threadIdx.x;
    const int* e = em + b*Ss;
    int base = tid * 8;
    int loc[8];
    int lsum = 0, lor = 0;
    #pragma unroll
    for (int i = 0; i < 8; ++i) { loc[i] = e[base + i]; lsum += loc[i]; lor |= loc[i]; }
    ssum[tid] = lor;
    __syncthreads();
    if (tid == 0) { int a = 0; for (int i = 0; i < 256; ++i) a |= ssum[i]; sany = a; }
    __syncthreads();
    int any = sany;
    __syncthreads();
    if (!any && tid == 255) { loc[7] = 1; lsum = 1; }
    int prev = (tid == 0) ? 1 : e[base - 1];
    if (!any && tid) prev = 0;
    int mk[8];
    int lmax = -1;
    #pragma unroll
    for (int i = 0; i < 8; ++i) {
        int pe = (i == 0) ? prev : loc[i - 1];
        if (i == 7 && !any && tid == 255) pe = e[base + 6];
        mk[i] = pe ? (base + i) : -1;
        lmax = max(lmax, mk[i]);
    }
    ssum[tid] = lsum; smax[tid] = lmax;
    __syncthreads();
    if (tid == 0) {
        int rs = 0, rm = -1;
        for (int i = 0; i < 256; ++i) {
            int ts = ssum[i], tm = smax[i];
            ssum[i] = rs; smax[i] = rm;
            rs += ts; rm = max(rm, tm);
        }
        stot = rs;
    }
    __syncthreads();
    int run = ssum[tid], rmax = smax[tid], tot = stot;
    int* cpb = cp + b*Ss;
    #pragma unroll
    for (int i = 0; i < 8; ++i) {
        int s = base + i;
        rmax = max(rmax, mk[i]);
        int chunk = run;
        run += loc[i];
        int pos = s - rmax;
        bool valid = (chunk < tot) && (chunk < MAXC) && (pos < MCL);
        cpb[s] = valid ? (chunk * MCL + pos) : -1;
    }
}

// ---------------- fill / scatter ----------------
__global__ void k_fill(float* __restrict__ out, const float* __restrict__ pad,
                       const int* __restrict__ padid) {
    int i = blockIdx.x * blockDim.x + threadIdx.x;
    constexpr int N4  = Bb * MAXC * MCL * D / 4;
    constexpr int NI4 = Bb * MAXC * MCL / 4;
    if (i < N4) {
        ((float4*)out)[i] = ((const float4*)pad)[i & 15];
    } else if (i < N4 + NI4) {
        float pv = (float)(*padid);
        float4 v; v.x = pv; v.y = pv; v.z = pv; v.w = pv;
        ((float4*)out)[i] = v;
    }
}

__global__ __launch_bounds__(256) void k_scatter(
    const float* __restrict__ X, const int* __restrict__ cp,
    const int* __restrict__ ids, float* __restrict__ out) {
    int tid = threadIdx.x;
    int w = tid >> 6, d = tid & 63;
    int t = blockIdx.x*4 + w;
    int c = cp[t];
    if (c < 0) return;
    int b = t >> 11;
    float* dst = out + ((size_t)(b * MAXC * MCL) + c) * D;
    dst[d] = X[t*D + d];
    if (d == 0)
        out[(size_t)Bb*MAXC*MCL*D + (size_t)b*MAXC*MCL + c] = (float)ids[t];
}

// ---------------- launch ----------------
extern "C" void kernel_launch(void* const* d_in, const int* in_sizes, int n_in,
                              void* d_out, int out_size, void* d_ws, size_t ws_size,
                              hipStream_t stream) {
    const float* x    = (const float*)d_in[0];
    const float* pad  = (const float*)d_in[1];
    const int*   xids = (const int*)  d_in[2];
    const int*   padid= (const int*)  d_in[3];
    const float* Wq   = (const float*)d_in[4];
    const float* Wk   = (const float*)d_in[5];
    const float* Wv   = (const float*)d_in[6];
    const float* Wo   = (const float*)d_in[7];
    const float* ln1  = (const float*)d_in[8];
    const float* ln2  = (const float*)d_in[9];
    const float* W1   = (const float*)d_in[10];
    const float* W2   = (const float*)d_in[11];
    const float* Wh   = (const float*)d_in[12];
    const float* bh   = (const float*)d_in[13];
    float* out = (float*)d_out;
    float* ws  = (float*)d_ws;

    float* X  = ws + WX;
    float* Qb = ws + WQ;
    float* KVb= ws + WKV;
    float* Ob = ws + WO;
    float* PBb= ws + WPB;
    float* Ub = ws + WU;
    float* L1b= ws + WL1;
    int*   EMb= (int*)(ws + WEM);
    int*   CPb= (int*)(ws + WCP);
    float* ct = ws + WCT;
    float* st = ws + WST;

    k_init<<<2048, 256, 0, stream>>>(x, X, ct, st);
    for (int l = 0; l < NL; ++l) {
        k_qkv <<<256, 256, 0, stream>>>(X, Wq + l*D*D, Wk + l*D*D, Wv + l*D*D,
                                        ln1 + l*D, ct, st, Qb, KVb);
        k_attn2<<<NTASK/4, 256, 0, stream>>>(Qb, KVb, PBb);
        k_comb <<<32*16, 128, 0, stream>>>(PBb, Ob);
        k_post1<<<256, 256, 0, stream>>>(X, Ob, Wo + l*D*D);
        k_ffn1<<<NT/16, 256, 0, stream>>>(X, ln2 + l*D, W1 + l*D*FFNx, Ub);
        k_ffn2<<<NT/16, 256, 0, stream>>>(X, Ub, W2 + l*FFNx*D);
    }
    k_head<<<NT/4, 256, 0, stream>>>(X, Wh, bh, L1b, EMb);
    k_reg <<<1, 256, 0, stream>>>(L1b, out + (size_t)Bb*MAXC*MCL*D + Bb*MAXC*MCL);
    k_scan<<<Bb, 256, 0, stream>>>(EMb, CPb);
    k_fill<<<(Bb*MAXC*MCL*D/4 + Bb*MAXC*MCL/4 + 255)/256, 256, 0, stream>>>(out, pad, padid);
    k_scatter<<<NT/4, 256, 0, stream>>>(X, CPb, xids, out);
}

// Round 6
// 455.733 us; speedup vs baseline: 1.2099x; 1.2099x over previous
//
#include <hip/hip_runtime.h>
#include <math.h>

// ---------------- problem constants (fixed by setup_inputs) ----------------
constexpr int D   = 64;
constexpr int H   = 8;
constexpr int HD  = 8;
constexpr int NL  = 3;
constexpr int FFNx= 256;
constexpr int Bb  = 4;
constexpr int Ss  = 2048;
constexpr int NT  = Bb * Ss;        // 8192 tokens
constexpr int MAXC= 1024;
constexpr int MCL = 16;

// attention task decomposition: uniform tasks, chunk-major enumeration
constexpr int QW   = 128;            // queries per wave (2 per lane)
constexpr int CH   = 128;            // keys per chunk task (== QW -> uniform)
constexpr int TPB  = 136;            // tasks per (b,h): sum_{s=0..15} (16-s)
constexpr int NTASK= 32 * TPB;       // 4352 waves
constexpr int PBSZ = 1152;           // floats per partial: l(128) + o(1024)

// ---------------- workspace layout (float elements) ----------------
constexpr size_t WX  = 0;                        // [NT*D] = 524288
constexpr size_t WQ  = 524288;                   // [NT*D] (U alias, needs NT*FFN)
constexpr size_t WKV = 2621440;                  // [32*2048*16] interleaved K|V
constexpr size_t WO  = 3670016;                  // [NT*D]
constexpr size_t WPB = 4194304;                  // [NTASK*PBSZ] attn partials
constexpr size_t WU  = WQ;                       // [NT*FFN] aliases Q
constexpr size_t WL1 = 9764864;                  // [NT]
constexpr size_t WEM = WL1 + NT;                 // [NT] int
constexpr size_t WCP = WEM + NT;                 // [NT] int
constexpr size_t WCT = WCP + NT;                 // [Ss*4]
constexpr size_t WST = WCT + Ss*4;               // [Ss*4]  (end ~9.81M floats)

constexpr float LOG2E = 1.4426950408889634f;

typedef float v2f __attribute__((ext_vector_type(2)));

__device__ __forceinline__ float rdlane(float v, int l) {
    return __builtin_bit_cast(float, __builtin_amdgcn_readlane(__builtin_bit_cast(int, v), l));
}

// ---------------- init: copy x -> X, build rope tables ----------------
__global__ void k_init(const float* __restrict__ x, float* __restrict__ X,
                       float* __restrict__ ct, float* __restrict__ st) {
    int i = blockIdx.x * blockDim.x + threadIdx.x;
    constexpr int N4 = NT * D / 4;
    if (i < N4) ((float4*)X)[i] = ((const float4*)x)[i];
    if (i < Ss * 4) {
        int s = i >> 2, f = i & 3;
        const float fr[4] = {1.0f, 0.1f, 0.01f, 0.001f};
        float ang = (float)s * fr[f];
        ct[i] = cosf(ang);
        st[i] = sinf(ang);
    }
}

// ---------------- rmsnorm + QKV + rope (wave-per-token, readlane bcast) ----
// Q -> [b,s,h*8+e]; K,V -> interleaved KV[bh][s][0..7=K, 8..15=V]
__global__ __launch_bounds__(256) void k_qkv(
    const float* __restrict__ X, const float* __restrict__ Wq,
    const float* __restrict__ Wk, const float* __restrict__ Wv,
    const float* __restrict__ g1, const float* __restrict__ ct,
    const float* __restrict__ st, float* __restrict__ Q,
    float* __restrict__ KV) {
    __shared__ float wq_s[D*D], wk_s[D*D], wv_s[D*D];
    __shared__ float g_s[D];
    int tid = threadIdx.x;
    for (int i = tid; i < D*D; i += 256) {
        wq_s[i] = Wq[i]; wk_s[i] = Wk[i]; wv_s[i] = Wv[i];
    }
    if (tid < D) g_s[tid] = g1[tid];
    __syncthreads();
    int w = tid >> 6, d = tid & 63;
    int t0 = blockIdx.x * 32;
    for (int it = 0; it < 8; ++it) {
        int t = t0 + it*4 + w;
        float xv = X[t*D + d];
        float ss = xv * xv;
        #pragma unroll
        for (int off = 32; off; off >>= 1) ss += __shfl_xor(ss, off);
        float r = 1.0f / sqrtf(ss * (1.0f/D) + 1e-6f);
        float h = xv * g_s[d] * r;
        float aq = 0.f, ak = 0.f, av = 0.f;
        #pragma unroll
        for (int j = 0; j < D; ++j) {
            float hj = rdlane(h, j);
            aq += hj * wq_s[j*D + d];
            ak += hj * wk_s[j*D + d];
            av += hj * wv_s[j*D + d];
        }
        int s  = t & (Ss - 1);
        int e  = d & 7;
        int fi = e & 3;
        float c  = ct[s*4 + fi];
        float sn = st[s*4 + fi];
        float pq = __shfl_xor(aq, 4);
        float pk = __shfl_xor(ak, 4);
        float rq, rk;
        if (e < 4) { rq = aq*c - pq*sn; rk = ak*c - pk*sn; }
        else       { rq = pq*sn + aq*c; rk = pk*sn + ak*c; }
        Q[t*D + d] = rq;
        int bq = t >> 11;
        int hh = d >> 3;
        float* kvp = KV + ((((size_t)(bq*H + hh))*Ss + s) << 4);
        kvp[e]     = rk;
        kvp[8 + e] = av;
    }
}

// ---------------- fused attention inner loop (fixed bias, packed f32) -----
template<bool DIAG>
__device__ __forceinline__ void attn_loop(
    const float4* __restrict__ kvb, int L,
    const v2f* __restrict__ q01, v2f& l01, v2f* __restrict__ oP) {
    for (int j0 = 0; j0 < CH; j0 += 16) {
        v2f p01[16];
        #pragma unroll
        for (int jj = 0; jj < 16; ++jj) {
            int j = j0 + jj;
            const float4* kv = kvb + (size_t)j*4;
            float4 ka = kv[0];
            float4 kb = kv[1];
            v2f acc;
            acc  = q01[0] * (v2f){ka.x, ka.x};
            acc += q01[1] * (v2f){ka.y, ka.y};
            acc += q01[2] * (v2f){ka.z, ka.z};
            acc += q01[3] * (v2f){ka.w, ka.w};
            acc += q01[4] * (v2f){kb.x, kb.x};
            acc += q01[5] * (v2f){kb.y, kb.y};
            acc += q01[6] * (v2f){kb.z, kb.z};
            acc += q01[7] * (v2f){kb.w, kb.w};
            if (DIAG) {
                if (j > L)      acc.x = -1e30f;
                if (j > L + 64) acc.y = -1e30f;
            }
            p01[jj].x = exp2f(acc.x);
            p01[jj].y = exp2f(acc.y);
        }
        #pragma unroll
        for (int jj = 0; jj < 16; ++jj) {
            int j = j0 + jj;
            const float4* kv = kvb + (size_t)j*4;
            float4 va = kv[2];
            float4 vb = kv[3];
            v2f p = p01[jj];
            l01 += p;
            oP[0] += p * (v2f){va.x, va.x};
            oP[1] += p * (v2f){va.y, va.y};
            oP[2] += p * (v2f){va.z, va.z};
            oP[3] += p * (v2f){va.w, va.w};
            oP[4] += p * (v2f){vb.x, vb.x};
            oP[5] += p * (v2f){vb.y, vb.y};
            oP[6] += p * (v2f){vb.z, vb.z};
            oP[7] += p * (v2f){vb.w, vb.w};
        }
    }
}

// ---------------- causal attention, uniform split-K, fixed-bias exp2 ------
// enumeration: s outer (off(s)=16s - s(s-1)/2), t = s..15 inner.
__global__ __launch_bounds__(256) void k_attn2(
    const float* __restrict__ Qg, const float* __restrict__ KV,
    float* __restrict__ PB) {
    int wid = (blockIdx.x << 2) + (threadIdx.x >> 6);
    int L = threadIdx.x & 63;
    int bh = wid / TPB;
    int rem = wid - bh * TPB;
    int s = 0;
    while (rem >= 16 - s) { rem -= 16 - s; ++s; }
    int t = s + rem;
    int b = bh >> 3, h = bh & 7;
    int qmin = t * QW;
    int k0 = s * CH;

    const float SC = 0.35355339059327373f * LOG2E;   // 1/sqrt(8) * log2(e)
    const float* qp = Qg + ((size_t)(b*Ss + qmin + L))*D + h*HD;
    float4 qa0 = *(const float4*)(qp);
    float4 qb0 = *(const float4*)(qp + 4);
    float4 qa1 = *(const float4*)(qp + 64*D);
    float4 qb1 = *(const float4*)(qp + 64*D + 4);
    v2f q01[8];
    q01[0] = (v2f){qa0.x*SC, qa1.x*SC};
    q01[1] = (v2f){qa0.y*SC, qa1.y*SC};
    q01[2] = (v2f){qa0.z*SC, qa1.z*SC};
    q01[3] = (v2f){qa0.w*SC, qa1.w*SC};
    q01[4] = (v2f){qb0.x*SC, qb1.x*SC};
    q01[5] = (v2f){qb0.y*SC, qb1.y*SC};
    q01[6] = (v2f){qb0.z*SC, qb1.z*SC};
    q01[7] = (v2f){qb0.w*SC, qb1.w*SC};

    v2f l01 = (v2f){0.f, 0.f};
    v2f oP[8];
    #pragma unroll
    for (int e = 0; e < 8; ++e) oP[e] = (v2f){0.f, 0.f};

    const float4* kvb = (const float4*)(KV + (((size_t)bh*Ss + k0) << 4));
    if (s == t) attn_loop<true >(kvb, L, q01, l01, oP);
    else        attn_loop<false>(kvb, L, q01, l01, oP);

    float* pb = PB + (size_t)wid * PBSZ;
    pb[L]      = l01.x;
    pb[64 + L] = l01.y;
    #pragma unroll
    for (int e = 0; e < 8; ++e) {
        pb[128 + e*128 + L]      = oP[e].x;
        pb[128 + e*128 + 64 + L] = oP[e].y;
    }
}

// ---------------- combine partials -> O (plain sums, fixed bias) ----------
__global__ __launch_bounds__(128) void k_comb(const float* __restrict__ PB,
                                              float* __restrict__ Og) {
    int qs = threadIdx.x;           // 0..127
    int t  = blockIdx.x & 15;
    int bh = blockIdx.x >> 4;
    int b = bh >> 3, h = bh & 7;
    float Lx = 0.f;
    float O[8] = {0,0,0,0,0,0,0,0};
    for (int s3 = 0; s3 <= t; ++s3) {
        int idx = 16*s3 - (s3*(s3-1))/2 + (t - s3);
        const float* pb = PB + (size_t)(bh*TPB + idx) * PBSZ;
        Lx += pb[qs];
        #pragma unroll
        for (int e = 0; e < 8; ++e) O[e] += pb[128 + e*128 + qs];
    }
    float inv = 1.0f / Lx;
    float* op = Og + ((size_t)(b*Ss + t*QW + qs))*D + h*HD;
    #pragma unroll
    for (int e = 0; e < 8; ++e) op[e] = O[e] * inv;
}

// ---------------- x += O @ Wo (readlane bcast) ----------------
__global__ __launch_bounds__(256) void k_post1(
    float* __restrict__ X, const float* __restrict__ Og,
    const float* __restrict__ Wo) {
    __shared__ float ws_[D*D];
    int tid = threadIdx.x;
    for (int i = tid; i < D*D; i += 256) ws_[i] = Wo[i];
    __syncthreads();
    int w = tid >> 6, d = tid & 63;
    int t0 = blockIdx.x * 32;
    for (int it = 0; it < 8; ++it) {
        int t = t0 + it*4 + w;
        float ov = Og[t*D + d];
        float a = 0.f;
        #pragma unroll
        for (int j = 0; j < D; ++j) a += rdlane(ov, j) * ws_[j*D + d];
        X[t*D + d] += a;
    }
}

// ---------------- rms2 + W1 + gelu -> U (transposed LDS, packed f32) ------
__global__ __launch_bounds__(256) void k_ffn1(
    const float* __restrict__ X, const float* __restrict__ g2,
    const float* __restrict__ W1, float* __restrict__ U) {
    __shared__ __align__(16) float h2t[64][20];   // [dim][token], 80B rows
    __shared__ float part[16][16];
    __shared__ float g_s[D];
    int tid = threadIdx.x;
    if (tid < D) g_s[tid] = g2[tid];
    int t0 = blockIdx.x * 16;
    int tk = tid >> 4, li = tid & 15;
    float x0 = X[(t0+tk)*D + li];
    float x1 = X[(t0+tk)*D + li + 16];
    float x2 = X[(t0+tk)*D + li + 32];
    float x3 = X[(t0+tk)*D + li + 48];
    part[tk][li] = x0*x0 + x1*x1 + x2*x2 + x3*x3;
    __syncthreads();
    if (tid < 16) {
        float s = 0.f;
        #pragma unroll
        for (int i = 0; i < 16; ++i) s += part[tid][i];
        part[tid][0] = 1.0f / sqrtf(s * (1.0f/D) + 1e-6f);
    }
    __syncthreads();
    float r = part[tk][0];
    h2t[li][tk]      = x0 * g_s[li]      * r;
    h2t[li + 16][tk] = x1 * g_s[li + 16] * r;
    h2t[li + 32][tk] = x2 * g_s[li + 32] * r;
    h2t[li + 48][tk] = x3 * g_s[li + 48] * r;
    __syncthreads();
    int f = tid;
    v2f acc2[8];
    #pragma unroll
    for (int i = 0; i < 8; ++i) acc2[i] = (v2f){0.f, 0.f};
    for (int j = 0; j < D; ++j) {
        float wv = W1[j*FFNx + f];
        v2f wv2 = (v2f){wv, wv};
        const float4* hp = (const float4*)&h2t[j][0];
        float4 a0 = hp[0], a1 = hp[1], a2 = hp[2], a3 = hp[3];
        const v2f* a0v = (const v2f*)&a0;
        const v2f* a1v = (const v2f*)&a1;
        const v2f* a2v = (const v2f*)&a2;
        const v2f* a3v = (const v2f*)&a3;
        acc2[0] += a0v[0]*wv2;  acc2[1] += a0v[1]*wv2;
        acc2[2] += a1v[0]*wv2;  acc2[3] += a1v[1]*wv2;
        acc2[4] += a2v[0]*wv2;  acc2[5] += a2v[1]*wv2;
        acc2[6] += a3v[0]*wv2;  acc2[7] += a3v[1]*wv2;
    }
    #pragma unroll
    for (int i = 0; i < 8; ++i) {
        float ua = acc2[i].x;
        float ub = acc2[i].y;
        ua = 0.5f * ua * (1.0f + erff(ua * 0.70710678118654752f));
        ub = 0.5f * ub * (1.0f + erff(ub * 0.70710678118654752f));
        U[(t0 + 2*i)*FFNx + f]     = ua;
        U[(t0 + 2*i + 1)*FFNx + f] = ub;
    }
}

// ---------------- x += U @ W2 (transposed LDS, packed f32) ----------------
__global__ __launch_bounds__(256) void k_ffn2(
    float* __restrict__ X, const float* __restrict__ U,
    const float* __restrict__ W2) {
    __shared__ __align__(16) float ult[FFNx][20];  // [f][token]
    __shared__ float red[4][16][D];
    int tid = threadIdx.x;
    int t0 = blockIdx.x * 16;
    #pragma unroll
    for (int k = 0; k < 16; ++k) ult[tid][k] = U[(t0 + k)*FFNx + tid];
    __syncthreads();
    int d = tid & 63, fp = tid >> 6;
    v2f acc2[8];
    #pragma unroll
    for (int i = 0; i < 8; ++i) acc2[i] = (v2f){0.f, 0.f};
    for (int fo = 0; fo < 64; ++fo) {
        int f = fp*64 + fo;
        float wv = W2[f*D + d];
        v2f wv2 = (v2f){wv, wv};
        const float4* up = (const float4*)&ult[f][0];
        float4 u0 = up[0], u1 = up[1], u2 = up[2], u3 = up[3];
        const v2f* u0v = (const v2f*)&u0;
        const v2f* u1v = (const v2f*)&u1;
        const v2f* u2v = (const v2f*)&u2;
        const v2f* u3v = (const v2f*)&u3;
        acc2[0] += u0v[0]*wv2;  acc2[1] += u0v[1]*wv2;
        acc2[2] += u1v[0]*wv2;  acc2[3] += u1v[1]*wv2;
        acc2[4] += u2v[0]*wv2;  acc2[5] += u2v[1]*wv2;
        acc2[6] += u3v[0]*wv2;  acc2[7] += u3v[1]*wv2;
    }
    #pragma unroll
    for (int i = 0; i < 8; ++i) {
        red[fp][2*i][d]     = acc2[i].x;
        red[fp][2*i + 1][d] = acc2[i].y;
    }
    __syncthreads();
    int tk = tid >> 6;
    #pragma unroll
    for (int k = 0; k < 4; ++k) {
        int tt = tk + k*4;
        float sum = red[0][tt][d] + red[1][tt][d] + red[2][tt][d] + red[3][tt][d];
        X[(t0 + tt)*D + d] += sum;
    }
}

// ---------------- head ----------------
__global__ __launch_bounds__(256) void k_head(
    const float* __restrict__ X, const float* __restrict__ Wh,
    const float* __restrict__ bh, float* __restrict__ logit1,
    int* __restrict__ em) {
    int tid = threadIdx.x;
    int w = tid >> 6, d = tid & 63;
    int t = blockIdx.x*4 + w;
    float xv = X[t*D + d];
    float p0 = xv * Wh[d*2];
    float p1 = xv * Wh[d*2 + 1];
    #pragma unroll
    for (int off = 32; off; off >>= 1) {
        p0 += __shfl_xor(p0, off);
        p1 += __shfl_xor(p1, off);
    }
    if (d == 0) {
        float l0 = p0 + bh[0], l1 = p1 + bh[1];
        em[t] = (l0 > l1) ? 1 : 0;
        logit1[t] = l1;
    }
}

// ---------------- reg term ----------------
__global__ void k_reg(const float* __restrict__ logit1, float* __restrict__ outreg) {
    __shared__ float red[256];
    int tid = threadIdx.x;
    float s = 0.f;
    for (int i = tid; i < NT; i += 256) s += logit1[i];
    red[tid] = s;
    __syncthreads();
    for (int off = 128; off; off >>= 1) {
        if (tid < off) red[tid] += red[tid + off];
        __syncthreads();
    }
    if (tid == 0) *outreg = red[0] * (1.0f / NT);
}

// ---------------- per-batch scan ----------------
__global__ __launch_bounds__(256) void k_scan(const int* __restrict__ em,
                                              int* __restrict__ cp) {
    __shared__ int ssum[256], smax[256];
    __shared__ int sany, stot;
    int b = blockIdx.x, tid = threadIdx.x;
    const int* e = em + b*Ss;
    int base = tid * 8;
    int loc[8];
    int lsum = 0, lor = 0;
    #pragma unroll
    for (int i = 0; i < 8; ++i) { loc[i] = e[base + i]; lsum += loc[i]; lor |= loc[i]; }
    ssum[tid] = lor;
    __syncthreads();
    if (tid == 0) { int a = 0; for (int i = 0; i < 256; ++i) a |= ssum[i]; sany = a; }
    __syncthreads();
    int any = sany;
    __syncthreads();
    if (!any && tid == 255) { loc[7] = 1; lsum = 1; }
    int prev = (tid == 0) ? 1 : e[base - 1];
    if (!any && tid) prev = 0;
    int mk[8];
    int lmax = -1;
    #pragma unroll
    for (int i = 0; i < 8; ++i) {
        int pe = (i == 0) ? prev : loc[i - 1];
        if (i == 7 && !any && tid == 255) pe = e[base + 6];
        mk[i] = pe ? (base + i) : -1;
        lmax = max(lmax, mk[i]);
    }
    ssum[tid] = lsum; smax[tid] = lmax;
    __syncthreads();
    if (tid == 0) {
        int rs = 0, rm = -1;
        for (int i = 0; i < 256; ++i) {
            int ts = ssum[i], tm = smax[i];
            ssum[i] = rs; smax[i] = rm;
            rs += ts; rm = max(rm, tm);
        }
        stot = rs;
    }
    __syncthreads();
    int run = ssum[tid], rmax = smax[tid], tot = stot;
    int* cpb = cp + b*Ss;
    #pragma unroll
    for (int i = 0; i < 8; ++i) {
        int s = base + i;
        rmax = max(rmax, mk[i]);
        int chunk = run;
        run += loc[i];
        int pos = s - rmax;
        bool valid = (chunk < tot) && (chunk < MAXC) && (pos < MCL);
        cpb[s] = valid ? (chunk * MCL + pos) : -1;
    }
}

// ---------------- fill / scatter ----------------
__global__ void k_fill(float* __restrict__ out, const float* __restrict__ pad,
                       const int* __restrict__ padid) {
    int i = blockIdx.x * blockDim.x + threadIdx.x;
    constexpr int N4  = Bb * MAXC * MCL * D / 4;
    constexpr int NI4 = Bb * MAXC * MCL / 4;
    if (i < N4) {
        ((float4*)out)[i] = ((const float4*)pad)[i & 15];
    } else if (i < N4 + NI4) {
        float pv = (float)(*padid);
        float4 v; v.x = pv; v.y = pv; v.z = pv; v.w = pv;
        ((float4*)out)[i] = v;
    }
}

__global__ __launch_bounds__(256) void k_scatter(
    const float* __restrict__ X, const int* __restrict__ cp,
    const int* __restrict__ ids, float* __restrict__ out) {
    int tid = threadIdx.x;
    int w = tid >> 6, d = tid & 63;
    int t = blockIdx.x*4 + w;
    int c = cp[t];
    if (c < 0) return;
    int b = t >> 11;
    float* dst = out + ((size_t)(b * MAXC * MCL) + c) * D;
    dst[d] = X[t*D + d];
    if (d == 0)
        out[(size_t)Bb*MAXC*MCL*D + (size_t)b*MAXC*MCL + c] = (float)ids[t];
}

// ---------------- launch ----------------
extern "C" void kernel_launch(void* const* d_in, const int* in_sizes, int n_in,
                              void* d_out, int out_size, void* d_ws, size_t ws_size,
                              hipStream_t stream) {
    const float* x    = (const float*)d_in[0];
    const float* pad  = (const float*)d_in[1];
    const int*   xids = (const int*)  d_in[2];
    const int*   padid= (const int*)  d_in[3];
    const float* Wq   = (const float*)d_in[4];
    const float* Wk   = (const float*)d_in[5];
    const float* Wv   = (const float*)d_in[6];
    const float* Wo   = (const float*)d_in[7];
    const float* ln1  = (const float*)d_in[8];
    const float* ln2  = (const float*)d_in[9];
    const float* W1   = (const float*)d_in[10];
    const float* W2   = (const float*)d_in[11];
    const float* Wh   = (const float*)d_in[12];
    const float* bh   = (const float*)d_in[13];
    float* out = (float*)d_out;
    float* ws  = (float*)d_ws;

    float* X  = ws + WX;
    float* Qb = ws + WQ;
    float* KVb= ws + WKV;
    float* Ob = ws + WO;
    float* PBb= ws + WPB;
    float* Ub = ws + WU;
    float* L1b= ws + WL1;
    int*   EMb= (int*)(ws + WEM);
    int*   CPb= (int*)(ws + WCP);
    float* ct = ws + WCT;
    float* st = ws + WST;

    k_init<<<2048, 256, 0, stream>>>(x, X, ct, st);
    for (int l = 0; l < NL; ++l) {
        k_qkv <<<256, 256, 0, stream>>>(X, Wq + l*D*D, Wk + l*D*D, Wv + l*D*D,
                                        ln1 + l*D, ct, st, Qb, KVb);
        k_attn2<<<NTASK/4, 256, 0, stream>>>(Qb, KVb, PBb);
        k_comb <<<32*16, 128, 0, stream>>>(PBb, Ob);
        k_post1<<<256, 256, 0, stream>>>(X, Ob, Wo + l*D*D);
        k_ffn1<<<NT/16, 256, 0, stream>>>(X, ln2 + l*D, W1 + l*D*FFNx, Ub);
        k_ffn2<<<NT/16, 256, 0, stream>>>(X, Ub, W2 + l*FFNx*D);
    }
    k_head<<<NT/4, 256, 0, stream>>>(X, Wh, bh, L1b, EMb);
    k_reg <<<1, 256, 0, stream>>>(L1b, out + (size_t)Bb*MAXC*MCL*D + Bb*MAXC*MCL);
    k_scan<<<Bb, 256, 0, stream>>>(EMb, CPb);
    k_fill<<<(Bb*MAXC*MCL*D/4 + Bb*MAXC*MCL/4 + 255)/256, 256, 0, stream>>>(out, pad, padid);
    k_scatter<<<NT/4, 256, 0, stream>>>(X, CPb, xids, out);
}

// Round 7
// 454.710 us; speedup vs baseline: 1.2126x; 1.0022x over previous
//
#include <hip/hip_runtime.h>
#include <math.h>

// ---------------- problem constants (fixed by setup_inputs) ----------------
constexpr int D   = 64;
constexpr int H   = 8;
constexpr int HD  = 8;
constexpr int NL  = 3;
constexpr int FFNx= 256;
constexpr int Bb  = 4;
constexpr int Ss  = 2048;
constexpr int NT  = Bb * Ss;        // 8192 tokens
constexpr int MAXC= 1024;
constexpr int MCL = 16;

// attention task decomposition: uniform tasks, chunk-major enumeration
constexpr int QW   = 128;            // queries per wave (2 per lane)
constexpr int CH   = 128;            // keys per chunk task (== QW -> uniform)
constexpr int TPB  = 136;            // tasks per (b,h): sum_{s=0..15} (16-s)
constexpr int BPB  = 34;             // blocks per (b,h) (4 waves each)
constexpr int NTASK= 32 * TPB;       // 4352 waves
constexpr int PBSZ = 1152;           // floats per partial: l(128) + o(1024)

// ---------------- workspace layout (float elements) ----------------
constexpr size_t WX  = 0;                        // [NT*D] = 524288
constexpr size_t WQ  = 524288;                   // [NT*D] (U alias, needs NT*FFN)
constexpr size_t WKV = 2621440;                  // [32*2048*16] interleaved K|V
constexpr size_t WO  = 3670016;                  // [NT*D]
constexpr size_t WPB = 4194304;                  // [NTASK*PBSZ] attn partials
constexpr size_t WU  = WQ;                       // [NT*FFN] aliases Q
constexpr size_t WL1 = 9764864;                  // [NT]
constexpr size_t WEM = WL1 + NT;                 // [NT] int
constexpr size_t WCP = WEM + NT;                 // [NT] int
constexpr size_t WCT = WCP + NT;                 // [Ss*4]
constexpr size_t WST = WCT + Ss*4;               // [Ss*4]  (end ~9.81M floats)

constexpr float LOG2E = 1.4426950408889634f;

typedef float v2f __attribute__((ext_vector_type(2)));

__device__ __forceinline__ float rdlane(float v, int l) {
    return __builtin_bit_cast(float, __builtin_amdgcn_readlane(__builtin_bit_cast(int, v), l));
}

// ---------------- init: copy x -> X, build rope tables ----------------
__global__ void k_init(const float* __restrict__ x, float* __restrict__ X,
                       float* __restrict__ ct, float* __restrict__ st) {
    int i = blockIdx.x * blockDim.x + threadIdx.x;
    constexpr int N4 = NT * D / 4;
    if (i < N4) ((float4*)X)[i] = ((const float4*)x)[i];
    if (i < Ss * 4) {
        int s = i >> 2, f = i & 3;
        const float fr[4] = {1.0f, 0.1f, 0.01f, 0.001f};
        float ang = (float)s * fr[f];
        ct[i] = cosf(ang);
        st[i] = sinf(ang);
    }
}

// ---------------- rmsnorm + QKV + rope (wave-per-token, readlane bcast) ----
// Q -> [b,s,h*8+e]; K,V -> interleaved KV[bh][s][0..7=K, 8..15=V]
__global__ __launch_bounds__(256) void k_qkv(
    const float* __restrict__ X, const float* __restrict__ Wq,
    const float* __restrict__ Wk, const float* __restrict__ Wv,
    const float* __restrict__ g1, const float* __restrict__ ct,
    const float* __restrict__ st, float* __restrict__ Q,
    float* __restrict__ KV) {
    __shared__ float wq_s[D*D], wk_s[D*D], wv_s[D*D];
    __shared__ float g_s[D];
    int tid = threadIdx.x;
    for (int i = tid; i < D*D; i += 256) {
        wq_s[i] = Wq[i]; wk_s[i] = Wk[i]; wv_s[i] = Wv[i];
    }
    if (tid < D) g_s[tid] = g1[tid];
    __syncthreads();
    int w = tid >> 6, d = tid & 63;
    int t0 = blockIdx.x * 32;
    for (int it = 0; it < 8; ++it) {
        int t = t0 + it*4 + w;
        float xv = X[t*D + d];
        float ss = xv * xv;
        #pragma unroll
        for (int off = 32; off; off >>= 1) ss += __shfl_xor(ss, off);
        float r = 1.0f / sqrtf(ss * (1.0f/D) + 1e-6f);
        float h = xv * g_s[d] * r;
        float aq = 0.f, ak = 0.f, av = 0.f;
        #pragma unroll
        for (int j = 0; j < D; ++j) {
            float hj = rdlane(h, j);
            aq += hj * wq_s[j*D + d];
            ak += hj * wk_s[j*D + d];
            av += hj * wv_s[j*D + d];
        }
        int s  = t & (Ss - 1);
        int e  = d & 7;
        int fi = e & 3;
        float c  = ct[s*4 + fi];
        float sn = st[s*4 + fi];
        float pq = __shfl_xor(aq, 4);
        float pk = __shfl_xor(ak, 4);
        float rq, rk;
        if (e < 4) { rq = aq*c - pq*sn; rk = ak*c - pk*sn; }
        else       { rq = pq*sn + aq*c; rk = pk*sn + ak*c; }
        Q[t*D + d] = rq;
        int bq = t >> 11;
        int hh = d >> 3;
        float* kvp = KV + ((((size_t)(bq*H + hh))*Ss + s) << 4);
        kvp[e]     = rk;
        kvp[8 + e] = av;
    }
}

// ---------------- fused attention inner loop (fixed bias, packed f32) -----
template<bool DIAG>
__device__ __forceinline__ void attn_loop(
    const float4* __restrict__ kvb, int L,
    const v2f* __restrict__ q01, v2f& l01, v2f* __restrict__ oP) {
    for (int j0 = 0; j0 < CH; j0 += 16) {
        v2f p01[16];
        #pragma unroll
        for (int jj = 0; jj < 16; ++jj) {
            int j = j0 + jj;
            const float4* kv = kvb + (size_t)j*4;
            float4 ka = kv[0];
            float4 kb = kv[1];
            v2f acc;
            acc  = q01[0] * (v2f){ka.x, ka.x};
            acc += q01[1] * (v2f){ka.y, ka.y};
            acc += q01[2] * (v2f){ka.z, ka.z};
            acc += q01[3] * (v2f){ka.w, ka.w};
            acc += q01[4] * (v2f){kb.x, kb.x};
            acc += q01[5] * (v2f){kb.y, kb.y};
            acc += q01[6] * (v2f){kb.z, kb.z};
            acc += q01[7] * (v2f){kb.w, kb.w};
            if (DIAG) {
                if (j > L)      acc.x = -1e30f;
                if (j > L + 64) acc.y = -1e30f;
            }
            p01[jj].x = exp2f(acc.x);
            p01[jj].y = exp2f(acc.y);
        }
        #pragma unroll
        for (int jj = 0; jj < 16; ++jj) {
            int j = j0 + jj;
            const float4* kv = kvb + (size_t)j*4;
            float4 va = kv[2];
            float4 vb = kv[3];
            v2f p = p01[jj];
            l01 += p;
            oP[0] += p * (v2f){va.x, va.x};
            oP[1] += p * (v2f){va.y, va.y};
            oP[2] += p * (v2f){va.z, va.z};
            oP[3] += p * (v2f){va.w, va.w};
            oP[4] += p * (v2f){vb.x, vb.x};
            oP[5] += p * (v2f){vb.y, vb.y};
            oP[6] += p * (v2f){vb.z, vb.z};
            oP[7] += p * (v2f){vb.w, vb.w};
        }
    }
}

// ---------------- causal attention, uniform split-K, XCD-pinned ----------
// blockIdx = xcd + 8*slot (round-robin dispatch puts blockIdx%8 on XCD);
// bh = (slot/34)*8 + xcd  ->  all 34 blocks of a bh land on ONE XCD,
// so its 128KB KV stays L2-resident (4 bh * 128KB = 512KB per XCD).
__global__ __launch_bounds__(256) void k_attn2(
    const float* __restrict__ Qg, const float* __restrict__ KV,
    float* __restrict__ PB) {
    int xcd  = blockIdx.x & 7;
    int slot = blockIdx.x >> 3;
    int bhg  = slot / BPB;
    int blk  = slot - bhg * BPB;
    int bh   = bhg * 8 + xcd;
    int widb = blk * 4 + (threadIdx.x >> 6);   // 0..135 within bh
    int L = threadIdx.x & 63;
    int rem = widb;
    int s = 0;
    while (rem >= 16 - s) { rem -= 16 - s; ++s; }
    int t = s + rem;
    int b = bh >> 3, h = bh & 7;
    int qmin = t * QW;
    int k0 = s * CH;

    const float SC = 0.35355339059327373f * LOG2E;   // 1/sqrt(8) * log2(e)
    const float* qp = Qg + ((size_t)(b*Ss + qmin + L))*D + h*HD;
    float4 qa0 = *(const float4*)(qp);
    float4 qb0 = *(const float4*)(qp + 4);
    float4 qa1 = *(const float4*)(qp + 64*D);
    float4 qb1 = *(const float4*)(qp + 64*D + 4);
    v2f q01[8];
    q01[0] = (v2f){qa0.x*SC, qa1.x*SC};
    q01[1] = (v2f){qa0.y*SC, qa1.y*SC};
    q01[2] = (v2f){qa0.z*SC, qa1.z*SC};
    q01[3] = (v2f){qa0.w*SC, qa1.w*SC};
    q01[4] = (v2f){qb0.x*SC, qb1.x*SC};
    q01[5] = (v2f){qb0.y*SC, qb1.y*SC};
    q01[6] = (v2f){qb0.z*SC, qb1.z*SC};
    q01[7] = (v2f){qb0.w*SC, qb1.w*SC};

    v2f l01 = (v2f){0.f, 0.f};
    v2f oP[8];
    #pragma unroll
    for (int e = 0; e < 8; ++e) oP[e] = (v2f){0.f, 0.f};

    const float4* kvb = (const float4*)(KV + (((size_t)bh*Ss + k0) << 4));
    if (s == t) attn_loop<true >(kvb, L, q01, l01, oP);
    else        attn_loop<false>(kvb, L, q01, l01, oP);

    float* pb = PB + ((size_t)bh * TPB + widb) * PBSZ;
    pb[L]      = l01.x;
    pb[64 + L] = l01.y;
    #pragma unroll
    for (int e = 0; e < 8; ++e) {
        pb[128 + e*128 + L]      = oP[e].x;
        pb[128 + e*128 + 64 + L] = oP[e].y;
    }
}

// ---------------- combine partials -> O (plain sums, fixed bias) ----------
__global__ __launch_bounds__(128) void k_comb(const float* __restrict__ PB,
                                              float* __restrict__ Og) {
    int qs = threadIdx.x;           // 0..127
    int t  = blockIdx.x & 15;
    int bh = blockIdx.x >> 4;
    int b = bh >> 3, h = bh & 7;
    float Lx = 0.f;
    float O[8] = {0,0,0,0,0,0,0,0};
    for (int s3 = 0; s3 <= t; ++s3) {
        int idx = 16*s3 - (s3*(s3-1))/2 + (t - s3);
        const float* pb = PB + (size_t)(bh*TPB + idx) * PBSZ;
        Lx += pb[qs];
        #pragma unroll
        for (int e = 0; e < 8; ++e) O[e] += pb[128 + e*128 + qs];
    }
    float inv = 1.0f / Lx;
    float* op = Og + ((size_t)(b*Ss + t*QW + qs))*D + h*HD;
    #pragma unroll
    for (int e = 0; e < 8; ++e) op[e] = O[e] * inv;
}

// ---------------- x += O @ Wo (readlane bcast) ----------------
__global__ __launch_bounds__(256) void k_post1(
    float* __restrict__ X, const float* __restrict__ Og,
    const float* __restrict__ Wo) {
    __shared__ float ws_[D*D];
    int tid = threadIdx.x;
    for (int i = tid; i < D*D; i += 256) ws_[i] = Wo[i];
    __syncthreads();
    int w = tid >> 6, d = tid & 63;
    int t0 = blockIdx.x * 32;
    for (int it = 0; it < 8; ++it) {
        int t = t0 + it*4 + w;
        float ov = Og[t*D + d];
        float a = 0.f;
        #pragma unroll
        for (int j = 0; j < D; ++j) a += rdlane(ov, j) * ws_[j*D + d];
        X[t*D + d] += a;
    }
}

// ---------------- rms2 + W1 + gelu -> U (transposed LDS, packed f32) ------
__global__ __launch_bounds__(256) void k_ffn1(
    const float* __restrict__ X, const float* __restrict__ g2,
    const float* __restrict__ W1, float* __restrict__ U) {
    __shared__ __align__(16) float h2t[64][20];   // [dim][token], 80B rows
    __shared__ float part[16][16];
    __shared__ float g_s[D];
    int tid = threadIdx.x;
    if (tid < D) g_s[tid] = g2[tid];
    int t0 = blockIdx.x * 16;
    int tk = tid >> 4, li = tid & 15;
    float x0 = X[(t0+tk)*D + li];
    float x1 = X[(t0+tk)*D + li + 16];
    float x2 = X[(t0+tk)*D + li + 32];
    float x3 = X[(t0+tk)*D + li + 48];
    part[tk][li] = x0*x0 + x1*x1 + x2*x2 + x3*x3;
    __syncthreads();
    if (tid < 16) {
        float s = 0.f;
        #pragma unroll
        for (int i = 0; i < 16; ++i) s += part[tid][i];
        part[tid][0] = 1.0f / sqrtf(s * (1.0f/D) + 1e-6f);
    }
    __syncthreads();
    float r = part[tk][0];
    h2t[li][tk]      = x0 * g_s[li]      * r;
    h2t[li + 16][tk] = x1 * g_s[li + 16] * r;
    h2t[li + 32][tk] = x2 * g_s[li + 32] * r;
    h2t[li + 48][tk] = x3 * g_s[li + 48] * r;
    __syncthreads();
    int f = tid;
    v2f acc2[8];
    #pragma unroll
    for (int i = 0; i < 8; ++i) acc2[i] = (v2f){0.f, 0.f};
    for (int j = 0; j < D; ++j) {
        float wv = W1[j*FFNx + f];
        v2f wv2 = (v2f){wv, wv};
        const float4* hp = (const float4*)&h2t[j][0];
        float4 a0 = hp[0], a1 = hp[1], a2 = hp[2], a3 = hp[3];
        const v2f* a0v = (const v2f*)&a0;
        const v2f* a1v = (const v2f*)&a1;
        const v2f* a2v = (const v2f*)&a2;
        const v2f* a3v = (const v2f*)&a3;
        acc2[0] += a0v[0]*wv2;  acc2[1] += a0v[1]*wv2;
        acc2[2] += a1v[0]*wv2;  acc2[3] += a1v[1]*wv2;
        acc2[4] += a2v[0]*wv2;  acc2[5] += a2v[1]*wv2;
        acc2[6] += a3v[0]*wv2;  acc2[7] += a3v[1]*wv2;
    }
    #pragma unroll
    for (int i = 0; i < 8; ++i) {
        float ua = acc2[i].x;
        float ub = acc2[i].y;
        ua = 0.5f * ua * (1.0f + erff(ua * 0.70710678118654752f));
        ub = 0.5f * ub * (1.0f + erff(ub * 0.70710678118654752f));
        U[(t0 + 2*i)*FFNx + f]     = ua;
        U[(t0 + 2*i + 1)*FFNx + f] = ub;
    }
}

// ---------------- x += U @ W2 (transposed LDS, packed f32) ----------------
__global__ __launch_bounds__(256) void k_ffn2(
    float* __restrict__ X, const float* __restrict__ U,
    const float* __restrict__ W2) {
    __shared__ __align__(16) float ult[FFNx][20];  // [f][token]
    __shared__ float red[4][16][D];
    int tid = threadIdx.x;
    int t0 = blockIdx.x * 16;
    #pragma unroll
    for (int k = 0; k < 16; ++k) ult[tid][k] = U[(t0 + k)*FFNx + tid];
    __syncthreads();
    int d = tid & 63, fp = tid >> 6;
    v2f acc2[8];
    #pragma unroll
    for (int i = 0; i < 8; ++i) acc2[i] = (v2f){0.f, 0.f};
    for (int fo = 0; fo < 64; ++fo) {
        int f = fp*64 + fo;
        float wv = W2[f*D + d];
        v2f wv2 = (v2f){wv, wv};
        const float4* up = (const float4*)&ult[f][0];
        float4 u0 = up[0], u1 = up[1], u2 = up[2], u3 = up[3];
        const v2f* u0v = (const v2f*)&u0;
        const v2f* u1v = (const v2f*)&u1;
        const v2f* u2v = (const v2f*)&u2;
        const v2f* u3v = (const v2f*)&u3;
        acc2[0] += u0v[0]*wv2;  acc2[1] += u0v[1]*wv2;
        acc2[2] += u1v[0]*wv2;  acc2[3] += u1v[1]*wv2;
        acc2[4] += u2v[0]*wv2;  acc2[5] += u2v[1]*wv2;
        acc2[6] += u3v[0]*wv2;  acc2[7] += u3v[1]*wv2;
    }
    #pragma unroll
    for (int i = 0; i < 8; ++i) {
        red[fp][2*i][d]     = acc2[i].x;
        red[fp][2*i + 1][d] = acc2[i].y;
    }
    __syncthreads();
    int tk = tid >> 6;
    #pragma unroll
    for (int k = 0; k < 4; ++k) {
        int tt = tk + k*4;
        float sum = red[0][tt][d] + red[1][tt][d] + red[2][tt][d] + red[3][tt][d];
        X[(t0 + tt)*D + d] += sum;
    }
}

// ---------------- head ----------------
__global__ __launch_bounds__(256) void k_head(
    const float* __restrict__ X, const float* __restrict__ Wh,
    const float* __restrict__ bh, float* __restrict__ logit1,
    int* __restrict__ em) {
    int tid = threadIdx.x;
    int w = tid >> 6, d = tid & 63;
    int t = blockIdx.x*4 + w;
    float xv = X[t*D + d];
    float p0 = xv * Wh[d*2];
    float p1 = xv * Wh[d*2 + 1];
    #pragma unroll
    for (int off = 32; off; off >>= 1) {
        p0 += __shfl_xor(p0, off);
        p1 += __shfl_xor(p1, off);
    }
    if (d == 0) {
        float l0 = p0 + bh[0], l1 = p1 + bh[1];
        em[t] = (l0 > l1) ? 1 : 0;
        logit1[t] = l1;
    }
}

// ---------------- reg term ----------------
__global__ void k_reg(const float* __restrict__ logit1, float* __restrict__ outreg) {
    __shared__ float red[256];
    int tid = threadIdx.x;
    float s = 0.f;
    for (int i = tid; i < NT; i += 256) s += logit1[i];
    red[tid] = s;
    __syncthreads();
    for (int off = 128; off; off >>= 1) {
        if (tid < off) red[tid] += red[tid + off];
        __syncthreads();
    }
    if (tid == 0) *outreg = red[0] * (1.0f / NT);
}

// ---------------- per-batch scan ----------------
__global__ __launch_bounds__(256) void k_scan(const int* __restrict__ em,
                                              int* __restrict__ cp) {
    __shared__ int ssum[256], smax[256];
    __shared__ int sany, stot;
    int b = blockIdx.x, tid = threadIdx.x;
    const int* e = em + b*Ss;
    int base = tid * 8;
    int loc[8];
    int lsum = 0, lor = 0;
    #pragma unroll
    for (int i = 0; i < 8; ++i) { loc[i] = e[base + i]; lsum += loc[i]; lor |= loc[i]; }
    ssum[tid] = lor;
    __syncthreads();
    if (tid == 0) { int a = 0; for (int i = 0; i < 256; ++i) a |= ssum[i]; sany = a; }
    __syncthreads();
    int any = sany;
    __syncthreads();
    if (!any && tid == 255) { loc[7] = 1; lsum = 1; }
    int prev = (tid == 0) ? 1 : e[base - 1];
    if (!any && tid) prev = 0;
    int mk[8];
    int lmax = -1;
    #pragma unroll
    for (int i = 0; i < 8; ++i) {
        int pe = (i == 0) ? prev : loc[i - 1];
        if (i == 7 && !any && tid == 255) pe = e[base + 6];
        mk[i] = pe ? (base + i) : -1;
        lmax = max(lmax, mk[i]);
    }
    ssum[tid] = lsum; smax[tid] = lmax;
    __syncthreads();
    if (tid == 0) {
        int rs = 0, rm = -1;
        for (int i = 0; i < 256; ++i) {
            int ts = ssum[i], tm = smax[i];
            ssum[i] = rs; smax[i] = rm;
            rs += ts; rm = max(rm, tm);
        }
        stot = rs;
    }
    __syncthreads();
    int run = ssum[tid], rmax = smax[tid], tot = stot;
    int* cpb = cp + b*Ss;
    #pragma unroll
    for (int i = 0; i < 8; ++i) {
        int s = base + i;
        rmax = max(rmax, mk[i]);
        int chunk = run;
        run += loc[i];
        int pos = s - rmax;
        bool valid = (chunk < tot) && (chunk < MAXC) && (pos < MCL);
        cpb[s] = valid ? (chunk * MCL + pos) : -1;
    }
}

// ---------------- fill / scatter ----------------
__global__ void k_fill(float* __restrict__ out, const float* __restrict__ pad,
                       const int* __restrict__ padid) {
    int i = blockIdx.x * blockDim.x + threadIdx.x;
    constexpr int N4  = Bb * MAXC * MCL * D / 4;
    constexpr int NI4 = Bb * MAXC * MCL / 4;
    if (i < N4) {
        ((float4*)out)[i] = ((const float4*)pad)[i & 15];
    } else if (i < N4 + NI4) {
        float pv = (float)(*padid);
        float4 v; v.x = pv; v.y = pv; v.z = pv; v.w = pv;
        ((float4*)out)[i] = v;
    }
}

__global__ __launch_bounds__(256) void k_scatter(
    const float* __restrict__ X, const int* __restrict__ cp,
    const int* __restrict__ ids, float* __restrict__ out) {
    int tid = threadIdx.x;
    int w = tid >> 6, d = tid & 63;
    int t = blockIdx.x*4 + w;
    int c = cp[t];
    if (c < 0) return;
    int b = t >> 11;
    float* dst = out + ((size_t)(b * MAXC * MCL) + c) * D;
    dst[d] = X[t*D + d];
    if (d == 0)
        out[(size_t)Bb*MAXC*MCL*D + (size_t)b*MAXC*MCL + c] = (float)ids[t];
}

// ---------------- launch ----------------
extern "C" void kernel_launch(void* const* d_in, const int* in_sizes, int n_in,
                              void* d_out, int out_size, void* d_ws, size_t ws_size,
                              hipStream_t stream) {
    const float* x    = (const float*)d_in[0];
    const float* pad  = (const float*)d_in[1];
    const int*   xids = (const int*)  d_in[2];
    const int*   padid= (const int*)  d_in[3];
    const float* Wq   = (const float*)d_in[4];
    const float* Wk   = (const float*)d_in[5];
    const float* Wv   = (const float*)d_in[6];
    const float* Wo   = (const float*)d_in[7];
    const float* ln1  = (const float*)d_in[8];
    const float* ln2  = (const float*)d_in[9];
    const float* W1   = (const float*)d_in[10];
    const float* W2   = (const float*)d_in[11];
    const float* Wh   = (const float*)d_in[12];
    const float* bh   = (const float*)d_in[13];
    float* out = (float*)d_out;
    float* ws  = (float*)d_ws;

    float* X  = ws + WX;
    float* Qb = ws + WQ;
    float* KVb= ws + WKV;
    float* Ob = ws + WO;
    float* PBb= ws + WPB;
    float* Ub = ws + WU;
    float* L1b= ws + WL1;
    int*   EMb= (int*)(ws + WEM);
    int*   CPb= (int*)(ws + WCP);
    float* ct = ws + WCT;
    float* st = ws + WST;

    k_init<<<2048, 256, 0, stream>>>(x, X, ct, st);
    for (int l = 0; l < NL; ++l) {
        k_qkv <<<256, 256, 0, stream>>>(X, Wq + l*D*D, Wk + l*D*D, Wv + l*D*D,
                                        ln1 + l*D, ct, st, Qb, KVb);
        k_attn2<<<NTASK/4, 256, 0, stream>>>(Qb, KVb, PBb);
        k_comb <<<32*16, 128, 0, stream>>>(PBb, Ob);
        k_post1<<<256, 256, 0, stream>>>(X, Ob, Wo + l*D*D);
        k_ffn1<<<NT/16, 256, 0, stream>>>(X, ln2 + l*D, W1 + l*D*FFNx, Ub);
        k_ffn2<<<NT/16, 256, 0, stream>>>(X, Ub, W2 + l*FFNx*D);
    }
    k_head<<<NT/4, 256, 0, stream>>>(X, Wh, bh, L1b, EMb);
    k_reg <<<1, 256, 0, stream>>>(L1b, out + (size_t)Bb*MAXC*MCL*D + Bb*MAXC*MCL);
    k_scan<<<Bb, 256, 0, stream>>>(EMb, CPb);
    k_fill<<<(Bb*MAXC*MCL*D/4 + Bb*MAXC*MCL/4 + 255)/256, 256, 0, stream>>>(out, pad, padid);
    k_scatter<<<NT/4, 256, 0, stream>>>(X, CPb, xids, out);
}